// Round 1
// baseline (682.596 us; speedup 1.0000x reference)
//
#include <hip/hip_runtime.h>
#include <hip/hip_bf16.h>
#include <stdint.h>

#define TTOK 8192          // B*N tokens
#define KDIM 1024
#define KHID 2048
#define NEXP 8
#define NPAIR 16384        // TTOK * top2

typedef __attribute__((ext_vector_type(8))) short bf16x8;
typedef __attribute__((ext_vector_type(4))) float f32x4;

__device__ __forceinline__ unsigned short f2bf(float f) {
  union { float f; uint32_t u; } v; v.f = f;
  uint32_t r = (v.u + 0x7FFFu + ((v.u >> 16) & 1u)) >> 16;
  return (unsigned short)r;
}
__device__ __forceinline__ uint32_t pack2(float a, float b) {
  return (uint32_t)f2bf(a) | ((uint32_t)f2bf(b) << 16);
}

// async global->LDS, 16B per lane; LDS dest is wave-uniform base + lane*16
__device__ __forceinline__ void llds16(const void* g, void* l) {
  __builtin_amdgcn_global_load_lds(
      (const __attribute__((address_space(1))) uint32_t*)g,
      (__attribute__((address_space(3))) uint32_t*)l, 16, 0, 0);
}

// ---------------- fp32 -> bf16 conversion of x, w1, w3, w2 ----------------
__global__ __launch_bounds__(256) void convert_kernel(
    const float4* __restrict__ x, const float4* __restrict__ w1,
    const float4* __restrict__ w3, const float4* __restrict__ w2,
    uint4* __restrict__ xb, uint4* __restrict__ w1b,
    uint4* __restrict__ w3b, uint4* __restrict__ w2b) {
  size_t u = (size_t)blockIdx.x * 256 + threadIdx.x;   // unit = 8 floats
  const size_t NX = (size_t)TTOK * KDIM / 8;           // 1048576
  const size_t NW = (size_t)NEXP * KHID * KDIM / 8;    // 2097152
  const float4* src; uint4* dst; size_t i;
  if (u < NX)               { src = x;  dst = xb;  i = u; }
  else if (u < NX + NW)     { src = w1; dst = w1b; i = u - NX; }
  else if (u < NX + 2 * NW) { src = w3; dst = w3b; i = u - NX - NW; }
  else if (u < NX + 3 * NW) { src = w2; dst = w2b; i = u - NX - 2 * NW; }
  else return;
  float4 a = src[2 * i], b = src[2 * i + 1];
  uint4 r;
  r.x = pack2(a.x, a.y); r.y = pack2(a.z, a.w);
  r.z = pack2(b.x, b.y); r.w = pack2(b.z, b.w);
  dst[i] = r;
}

// ---------------- router: fp64 logits, top-2, softmax ----------------
// meta layout (ints): [0..7] counts, [8..16] offsets, [17..24] cursors
__global__ __launch_bounds__(256) void router_kernel(
    const float* __restrict__ x, const float* __restrict__ rwgt,
    float* __restrict__ dout, int* __restrict__ sel, float* __restrict__ rwt,
    int* __restrict__ meta) {
  __shared__ float rl[NEXP * KDIM];   // 32 KB
  for (int i = threadIdx.x; i < NEXP * KDIM / 4; i += 256)
    ((float4*)rl)[i] = ((const float4*)rwgt)[i];
  __syncthreads();
  int wid = threadIdx.x >> 6, lane = threadIdx.x & 63;
  int t = blockIdx.x * 4 + wid;
  const float* xt = x + (size_t)t * KDIM;
  float xf[16];
#pragma unroll
  for (int i = 0; i < 16; i++) xf[i] = xt[lane + 64 * i];
  double acc[NEXP];
#pragma unroll
  for (int e = 0; e < NEXP; e++) {
    double a = 0.0;
    const float* re = rl + e * KDIM;
#pragma unroll
    for (int i = 0; i < 16; i++) a += (double)xf[i] * (double)re[lane + 64 * i];
#pragma unroll
    for (int off = 32; off > 0; off >>= 1) a += __shfl_xor(a, off);
    acc[e] = a;
  }
  if (lane == 0) {
    int e1 = 0; double l1 = acc[0];
#pragma unroll
    for (int e = 1; e < NEXP; e++) if (acc[e] > l1) { l1 = acc[e]; e1 = e; }
    int e2 = (e1 == 0) ? 1 : 0; double l2 = acc[e2];
#pragma unroll
    for (int e = 0; e < NEXP; e++)
      if (e != e1 && e != e2 && acc[e] > l2) { l2 = acc[e]; e2 = e; }
    double p2 = exp(l2 - l1);
    double s = 1.0 + p2;
    float wa = (float)(1.0 / s), wb = (float)(p2 / s);
    float* rw_out = dout + (size_t)TTOK * KDIM;
    float* sel_out = rw_out + (size_t)TTOK * 2;
    rw_out[2 * t] = wa;  rw_out[2 * t + 1] = wb;
    sel_out[2 * t] = (float)e1;  sel_out[2 * t + 1] = (float)e2;
    sel[2 * t] = e1;  sel[2 * t + 1] = e2;
    rwt[2 * t] = wa;  rwt[2 * t + 1] = wb;
    atomicAdd(&meta[e1], 1);  atomicAdd(&meta[e2], 1);
  }
}

__global__ void scan_kernel(int* meta) {
  if (threadIdx.x == 0 && blockIdx.x == 0) {
    int o = 0;
#pragma unroll
    for (int e = 0; e < NEXP; e++) { meta[8 + e] = o; o += meta[e]; meta[17 + e] = 0; }
    meta[16] = o;
  }
}

__global__ __launch_bounds__(256) void fill_kernel(
    const int* __restrict__ sel, const float* __restrict__ rwt,
    int* __restrict__ meta, int* __restrict__ ptok, float* __restrict__ prw) {
  int i = blockIdx.x * 256 + threadIdx.x;   // pair index = t*2 + k
  if (i >= NPAIR) return;
  int e = sel[i];
  int slot = atomicAdd(&meta[17 + e], 1);
  int row = meta[8 + e] + slot;
  ptok[row] = i >> 1;
  prw[row] = rwt[i];
}

// ---------------- GEMM1: hidden = silu(Xg @ w1^T) * (Xg @ w3^T) ----------------
// grid: (HID/128, 64 max m-tiles, E); block 256 (4 waves, 2x2 of 64x64)
__global__ __launch_bounds__(256, 2) void gemm1_kernel(
    const unsigned short* __restrict__ xb, const unsigned short* __restrict__ w1b,
    const unsigned short* __restrict__ w3b, const int* __restrict__ meta,
    const int* __restrict__ ptok, unsigned short* __restrict__ hid) {
  int e = blockIdx.z;
  int cnt = meta[e];
  int m0 = blockIdx.y * 128;
  if (m0 >= cnt) return;
  int off = meta[8 + e];
  int n0 = blockIdx.x * 128;

  __shared__ unsigned short As[128 * 64];
  __shared__ unsigned short B1s[128 * 64];
  __shared__ unsigned short B3s[128 * 64];

  const int tid = threadIdx.x, wid = tid >> 6, lane = tid & 63;
  const int rl8 = lane >> 3, c16 = lane & 7;

  const unsigned short* a_src[4];
  const unsigned short* b1_src[4];
  const unsigned short* b3_src[4];
#pragma unroll
  for (int i = 0; i < 4; i++) {
    int m = wid * 32 + i * 8 + rl8;
    int gm = off + m0 + m; if (gm > NPAIR - 1) gm = NPAIR - 1;
    int tok = ptok[gm];
    a_src[i] = xb + (size_t)tok * KDIM + c16 * 8;
    int nrow = n0 + m;
    b1_src[i] = w1b + ((size_t)e * KHID + nrow) * KDIM + c16 * 8;
    b3_src[i] = w3b + ((size_t)e * KHID + nrow) * KDIM + c16 * 8;
  }

  f32x4 acc1[4][4] = {};
  f32x4 acc3[4][4] = {};
  const int wr = (wid >> 1) * 64, wc = (wid & 1) * 64;

  for (int kt = 0; kt < KDIM / 64; ++kt) {
    int kof = kt * 64;
#pragma unroll
    for (int i = 0; i < 4; i++) {
      llds16(a_src[i] + kof,  &As[(wid * 32 + i * 8) * 64]);
      llds16(b1_src[i] + kof, &B1s[(wid * 32 + i * 8) * 64]);
      llds16(b3_src[i] + kof, &B3s[(wid * 32 + i * 8) * 64]);
    }
    __syncthreads();
#pragma unroll
    for (int ks = 0; ks < 2; ++ks) {
      const int kr = ks * 32 + (lane >> 4) * 8;
      bf16x8 af[4], bf1[4], bf3[4];
#pragma unroll
      for (int i = 0; i < 4; i++)
        af[i] = *(const bf16x8*)&As[(wr + i * 16 + (lane & 15)) * 64 + kr];
#pragma unroll
      for (int j = 0; j < 4; j++) {
        bf1[j] = *(const bf16x8*)&B1s[(wc + j * 16 + (lane & 15)) * 64 + kr];
        bf3[j] = *(const bf16x8*)&B3s[(wc + j * 16 + (lane & 15)) * 64 + kr];
      }
#pragma unroll
      for (int i = 0; i < 4; i++)
#pragma unroll
        for (int j = 0; j < 4; j++) {
          acc1[i][j] = __builtin_amdgcn_mfma_f32_16x16x32_bf16(af[i], bf1[j], acc1[i][j], 0, 0, 0);
          acc3[i][j] = __builtin_amdgcn_mfma_f32_16x16x32_bf16(af[i], bf3[j], acc3[i][j], 0, 0, 0);
        }
    }
    __syncthreads();
  }

  const int c4 = (lane >> 4) * 4, cc = lane & 15;
#pragma unroll
  for (int i = 0; i < 4; i++) {
#pragma unroll
    for (int r = 0; r < 4; r++) {
      int lm = wr + i * 16 + c4 + r;
      if (m0 + lm < cnt) {   // mask: don't write into next expert's rows
        size_t rowbase = (size_t)(off + m0 + lm) * KHID + n0 + wc;
#pragma unroll
        for (int j = 0; j < 4; j++) {
          float v1 = acc1[i][j][r], v3 = acc3[i][j][r];
          float h = v1 / (1.0f + __expf(-v1)) * v3;
          hid[rowbase + j * 16 + cc] = f2bf(h);
        }
      }
    }
  }
}

// ---------------- GEMM2: out[tok] += rw * (hidden @ w2^T) ----------------
// grid: (DIM/128, 64 max m-tiles, E); block 256
__global__ __launch_bounds__(256, 2) void gemm2_kernel(
    const unsigned short* __restrict__ hid, const unsigned short* __restrict__ w2b,
    const int* __restrict__ meta, const int* __restrict__ ptok,
    const float* __restrict__ prw, float* __restrict__ out) {
  int e = blockIdx.z;
  int cnt = meta[e];
  int m0 = blockIdx.y * 128;
  if (m0 >= cnt) return;
  int off = meta[8 + e];
  int n0 = blockIdx.x * 128;

  __shared__ unsigned short As[128 * 64];
  __shared__ unsigned short Bs[128 * 64];

  const int tid = threadIdx.x, wid = tid >> 6, lane = tid & 63;
  const int rl8 = lane >> 3, c16 = lane & 7;

  const unsigned short* a_src[4];
  const unsigned short* b_src[4];
#pragma unroll
  for (int i = 0; i < 4; i++) {
    int m = wid * 32 + i * 8 + rl8;
    a_src[i] = hid + (size_t)(off + m0 + m) * KHID + c16 * 8;  // hid has +128 row pad
    b_src[i] = w2b + ((size_t)e * KDIM + n0 + m) * KHID + c16 * 8;
  }

  f32x4 acc[4][4] = {};
  const int wr = (wid >> 1) * 64, wc = (wid & 1) * 64;

  for (int kt = 0; kt < KHID / 64; ++kt) {
    int kof = kt * 64;
#pragma unroll
    for (int i = 0; i < 4; i++) {
      llds16(a_src[i] + kof, &As[(wid * 32 + i * 8) * 64]);
      llds16(b_src[i] + kof, &Bs[(wid * 32 + i * 8) * 64]);
    }
    __syncthreads();
#pragma unroll
    for (int ks = 0; ks < 2; ++ks) {
      const int kr = ks * 32 + (lane >> 4) * 8;
      bf16x8 af[4], bfb[4];
#pragma unroll
      for (int i = 0; i < 4; i++)
        af[i] = *(const bf16x8*)&As[(wr + i * 16 + (lane & 15)) * 64 + kr];
#pragma unroll
      for (int j = 0; j < 4; j++)
        bfb[j] = *(const bf16x8*)&Bs[(wc + j * 16 + (lane & 15)) * 64 + kr];
#pragma unroll
      for (int i = 0; i < 4; i++)
#pragma unroll
        for (int j = 0; j < 4; j++)
          acc[i][j] = __builtin_amdgcn_mfma_f32_16x16x32_bf16(af[i], bfb[j], acc[i][j], 0, 0, 0);
    }
    __syncthreads();
  }

  const int c4 = (lane >> 4) * 4, cc = lane & 15;
#pragma unroll
  for (int i = 0; i < 4; i++) {
#pragma unroll
    for (int r = 0; r < 4; r++) {
      int lm = wr + i * 16 + c4 + r;
      if (m0 + lm < cnt) {
        int row = off + m0 + lm;
        int tok = ptok[row];
        float w = prw[row];
        float* op = out + (size_t)tok * KDIM + n0 + wc;
#pragma unroll
        for (int j = 0; j < 4; j++)
          unsafeAtomicAdd(&op[j * 16 + cc], acc[i][j][r] * w);
      }
    }
  }
}

extern "C" void kernel_launch(void* const* d_in, const int* in_sizes, int n_in,
                              void* d_out, int out_size, void* d_ws, size_t ws_size,
                              hipStream_t stream) {
  const float* x    = (const float*)d_in[0];
  const float* rwgt = (const float*)d_in[1];
  const float* w1   = (const float*)d_in[2];
  const float* w3   = (const float*)d_in[3];
  const float* w2   = (const float*)d_in[4];
  float* out = (float*)d_out;

  char* ws = (char*)d_ws;
  const size_t OFF_META = 0;
  const size_t OFF_SEL  = 512;
  const size_t OFF_RWT  = OFF_SEL  + (size_t)NPAIR * 4;
  const size_t OFF_PTOK = OFF_RWT  + (size_t)NPAIR * 4;
  const size_t OFF_PRW  = OFF_PTOK + (size_t)NPAIR * 4;
  const size_t OFF_XB   = OFF_PRW  + (size_t)NPAIR * 4;                 // 512-aligned
  const size_t OFF_W1B  = OFF_XB   + (size_t)TTOK * KDIM * 2;
  const size_t OFF_W3B  = OFF_W1B  + (size_t)NEXP * KHID * KDIM * 2;
  const size_t OFF_W2B  = OFF_W3B  + (size_t)NEXP * KHID * KDIM * 2;
  const size_t OFF_HID  = OFF_W2B  + (size_t)NEXP * KDIM * KHID * 2;
  const size_t END      = OFF_HID  + (size_t)(NPAIR + 128) * KHID * 2;  // ~177 MiB
  if (ws_size < END) return;  // ws too small: fail safely (visible as absmax fail)

  int*   meta = (int*)(ws + OFF_META);
  int*   sel  = (int*)(ws + OFF_SEL);
  float* rwt  = (float*)(ws + OFF_RWT);
  int*   ptok = (int*)(ws + OFF_PTOK);
  float* prw  = (float*)(ws + OFF_PRW);
  unsigned short* xb  = (unsigned short*)(ws + OFF_XB);
  unsigned short* w1b = (unsigned short*)(ws + OFF_W1B);
  unsigned short* w3b = (unsigned short*)(ws + OFF_W3B);
  unsigned short* w2b = (unsigned short*)(ws + OFF_W2B);
  unsigned short* hid = (unsigned short*)(ws + OFF_HID);

  hipMemsetAsync(d_out, 0, (size_t)out_size * 4, stream);
  hipMemsetAsync(meta, 0, 512, stream);

  convert_kernel<<<28672, 256, 0, stream>>>(
      (const float4*)x, (const float4*)w1, (const float4*)w3, (const float4*)w2,
      (uint4*)xb, (uint4*)w1b, (uint4*)w3b, (uint4*)w2b);
  router_kernel<<<TTOK / 4, 256, 0, stream>>>(x, rwgt, out, sel, rwt, meta);
  scan_kernel<<<1, 64, 0, stream>>>(meta);
  fill_kernel<<<NPAIR / 256, 256, 0, stream>>>(sel, rwt, meta, ptok, prw);
  gemm1_kernel<<<dim3(KHID / 128, 64, NEXP), 256, 0, stream>>>(xb, w1b, w3b, meta, ptok, hid);
  gemm2_kernel<<<dim3(KDIM / 128, 64, NEXP), 256, 0, stream>>>(hid, w2b, meta, ptok, prw, out);
}

// Round 2
// 680.637 us; speedup vs baseline: 1.0029x; 1.0029x over previous
//
#include <hip/hip_runtime.h>
#include <hip/hip_bf16.h>
#include <stdint.h>

#define TTOK 8192          // B*N tokens
#define KDIM 1024
#define KHID 2048
#define NEXP 8
#define NPAIR 16384        // TTOK * top2

typedef __attribute__((ext_vector_type(8))) short bf16x8;
typedef __attribute__((ext_vector_type(4))) float f32x4;

__device__ __forceinline__ unsigned short f2bf(float f) {
  union { float f; uint32_t u; } v; v.f = f;
  uint32_t r = (v.u + 0x7FFFu + ((v.u >> 16) & 1u)) >> 16;
  return (unsigned short)r;
}
__device__ __forceinline__ uint32_t pack2(float a, float b) {
  return (uint32_t)f2bf(a) | ((uint32_t)f2bf(b) << 16);
}

// async global->LDS, 16B per lane; LDS dest is wave-uniform base + lane*16
__device__ __forceinline__ void llds16(const void* g, void* l) {
  __builtin_amdgcn_global_load_lds(
      (const __attribute__((address_space(1))) uint32_t*)g,
      (__attribute__((address_space(3))) uint32_t*)l, 16, 0, 0);
}

__device__ __forceinline__ f32x4 MF(bf16x8 a, bf16x8 b, f32x4 c) {
  return __builtin_amdgcn_mfma_f32_16x16x32_bf16(a, b, c, 0, 0, 0);
}

// ---------------- fp32 -> bf16 conversion of x, w1, w3, w2 ----------------
__global__ __launch_bounds__(256) void convert_kernel(
    const float4* __restrict__ x, const float4* __restrict__ w1,
    const float4* __restrict__ w3, const float4* __restrict__ w2,
    uint4* __restrict__ xb, uint4* __restrict__ w1b,
    uint4* __restrict__ w3b, uint4* __restrict__ w2b) {
  size_t u = (size_t)blockIdx.x * 256 + threadIdx.x;   // unit = 8 floats
  const size_t NX = (size_t)TTOK * KDIM / 8;           // 1048576
  const size_t NW = (size_t)NEXP * KHID * KDIM / 8;    // 2097152
  const float4* src; uint4* dst; size_t i;
  if (u < NX)               { src = x;  dst = xb;  i = u; }
  else if (u < NX + NW)     { src = w1; dst = w1b; i = u - NX; }
  else if (u < NX + 2 * NW) { src = w3; dst = w3b; i = u - NX - NW; }
  else if (u < NX + 3 * NW) { src = w2; dst = w2b; i = u - NX - 2 * NW; }
  else return;
  float4 a = src[2 * i], b = src[2 * i + 1];
  uint4 r;
  r.x = pack2(a.x, a.y); r.y = pack2(a.z, a.w);
  r.z = pack2(b.x, b.y); r.w = pack2(b.z, b.w);
  dst[i] = r;
}

// ---------------- router: fp64 logits, top-2, softmax ----------------
// meta layout (ints): [0..7] counts, [8..16] offsets, [17..24] cursors
__global__ __launch_bounds__(256) void router_kernel(
    const float* __restrict__ x, const float* __restrict__ rwgt,
    float* __restrict__ dout, int* __restrict__ sel, float* __restrict__ rwt,
    int* __restrict__ meta) {
  __shared__ float rl[NEXP * KDIM];   // 32 KB
  for (int i = threadIdx.x; i < NEXP * KDIM / 4; i += 256)
    ((float4*)rl)[i] = ((const float4*)rwgt)[i];
  __syncthreads();
  int wid = threadIdx.x >> 6, lane = threadIdx.x & 63;
  int t = blockIdx.x * 4 + wid;
  const float* xt = x + (size_t)t * KDIM;
  float xf[16];
#pragma unroll
  for (int i = 0; i < 16; i++) xf[i] = xt[lane + 64 * i];
  double acc[NEXP];
#pragma unroll
  for (int e = 0; e < NEXP; e++) {
    double a = 0.0;
    const float* re = rl + e * KDIM;
#pragma unroll
    for (int i = 0; i < 16; i++) a += (double)xf[i] * (double)re[lane + 64 * i];
#pragma unroll
    for (int off = 32; off > 0; off >>= 1) a += __shfl_xor(a, off);
    acc[e] = a;
  }
  if (lane == 0) {
    int e1 = 0; double l1 = acc[0];
#pragma unroll
    for (int e = 1; e < NEXP; e++) if (acc[e] > l1) { l1 = acc[e]; e1 = e; }
    int e2 = (e1 == 0) ? 1 : 0; double l2 = acc[e2];
#pragma unroll
    for (int e = 0; e < NEXP; e++)
      if (e != e1 && e != e2 && acc[e] > l2) { l2 = acc[e]; e2 = e; }
    double p2 = exp(l2 - l1);
    double s = 1.0 + p2;
    float wa = (float)(1.0 / s), wb = (float)(p2 / s);
    float* rw_out = dout + (size_t)TTOK * KDIM;
    float* sel_out = rw_out + (size_t)TTOK * 2;
    rw_out[2 * t] = wa;  rw_out[2 * t + 1] = wb;
    sel_out[2 * t] = (float)e1;  sel_out[2 * t + 1] = (float)e2;
    sel[2 * t] = e1;  sel[2 * t + 1] = e2;
    rwt[2 * t] = wa;  rwt[2 * t + 1] = wb;
    atomicAdd(&meta[e1], 1);  atomicAdd(&meta[e2], 1);
  }
}

__global__ void scan_kernel(int* meta) {
  if (threadIdx.x == 0 && blockIdx.x == 0) {
    int o = 0;
#pragma unroll
    for (int e = 0; e < NEXP; e++) { meta[8 + e] = o; o += meta[e]; meta[17 + e] = 0; }
    meta[16] = o;
  }
}

__global__ __launch_bounds__(256) void fill_kernel(
    const int* __restrict__ sel, const float* __restrict__ rwt,
    int* __restrict__ meta, int* __restrict__ ptok, float* __restrict__ prw) {
  int i = blockIdx.x * 256 + threadIdx.x;   // pair index = t*2 + k
  if (i >= NPAIR) return;
  int e = sel[i];
  int slot = atomicAdd(&meta[17 + e], 1);
  int row = meta[8 + e] + slot;
  ptok[row] = i >> 1;
  prw[row] = rwt[i];
}

// ---------------- 256x256 / BK=64 / 8-wave / double-buffered 4-phase GEMM ----------------
// G=1: hidden = silu(Xg @ w1^T) * (Xg @ w3^T). B-tile = [128 w1-rows ; 128 w3-rows] for the
//      SAME 128 hid columns; v3-waves (wn>=2) pass f32 acc to v1-waves through LDS epilogue.
// G=2: out[tok] += prw * (hidden @ w2^T), atomic accumulate.
template<int G>
__global__ __launch_bounds__(512, 2) void gemm8p_kernel(
    const unsigned short* __restrict__ A,
    const unsigned short* __restrict__ B0,
    const unsigned short* __restrict__ B1,
    const int* __restrict__ meta,
    const int* __restrict__ ptok,
    const float* __restrict__ prw,
    unsigned short* __restrict__ hid_out,
    float* __restrict__ out) {
  constexpr int KK = (G == 1) ? KDIM : KHID;   // inner dim (A and B row stride)
  constexpr int NT = KK / 64;

  const int e = blockIdx.z;
  const int cnt = meta[e];
  const int m0 = blockIdx.y * 256;
  if (m0 >= cnt) return;
  const int off = meta[8 + e];
  const int nb = blockIdx.x;

  // staging: [buf(2)][A/B(2)][256*64] bf16 = 128 KiB; epilogue reuses as f32
  __shared__ unsigned short lds[2 * 2 * 16384];

  const int tid = threadIdx.x;
  const int wid = tid >> 6, lane = tid & 63;
  const int wm = wid >> 2, wn = wid & 3;
  const int cc = lane & 15, hi = lane >> 4;

  // ---- staging source setup (pre-swizzled global column: col8_g = col8 ^ (row&7)) ----
  const int srow = tid >> 3;                         // 0..63: row within 64-row chunk
  const int scol = (((tid & 7) ^ (srow & 7)) << 3);  // element offset
  const unsigned short* asrc[4];
  const unsigned short* bsrc[4];
#pragma unroll
  for (int s = 0; s < 4; ++s) {
    int ar = m0 + s * 64 + srow;
    if (ar > cnt - 1) ar = cnt - 1;
    if (G == 1) {
      int tok = ptok[off + ar];
      asrc[s] = A + (size_t)tok * KK + scol;
    } else {
      asrc[s] = A + (size_t)(off + ar) * KK + scol;
    }
    if (G == 1) {
      int brow = nb * 128 + (s & 1) * 64 + srow;     // s<2: w1 rows, s>=2: w3 rows
      const unsigned short* bb = (s < 2) ? B0 : B1;
      bsrc[s] = bb + ((size_t)e * KHID + brow) * KK + scol;
    } else {
      int brow = nb * 256 + s * 64 + srow;
      bsrc[s] = B0 + ((size_t)e * KDIM + brow) * KK + scol;
    }
  }

  auto stageA = [&](int buf, int kt) {
    unsigned short* d = lds + buf * 32768;
#pragma unroll
    for (int s = 0; s < 4; ++s)
      llds16(asrc[s] + kt * 64, d + (s * 64 + wid * 8) * 64);
  };
  auto stageB = [&](int buf, int kt) {
    unsigned short* d = lds + buf * 32768 + 16384;
#pragma unroll
    for (int s = 0; s < 4; ++s)
      llds16(bsrc[s] + kt * 64, d + (s * 64 + wid * 8) * 64);
  };

  // ---- swizzled LDS read offsets: col8 = (ks*4+hi) ^ (row&7); row&7 == cc&7 always ----
  const int sw0 = ((hi) ^ (cc & 7)) << 3;            // ks=0, elements
  const int sw1 = ((4 + hi) ^ (cc & 7)) << 3;        // ks=1

  f32x4 acc[8][4] = {};
  bf16x8 areg[4][2], breg[4][2];

  // prologue: stage tiles 0 and 1
  stageA(0, 0); stageB(0, 0); stageA(1, 1); stageB(1, 1);
  asm volatile("s_waitcnt vmcnt(8)" ::: "memory");   // tile 0 landed
  __builtin_amdgcn_s_barrier();

#pragma unroll 1
  for (int kt = 0; kt < NT; ++kt) {
    const int p = kt & 1;
    const int ts = (kt + 2 < NT) ? kt + 2 : NT - 1;  // clamp keeps vmcnt static; safe by phase invariant
    const unsigned short* Ab = lds + p * 32768;
    const unsigned short* Bb = Ab + 16384;

    // ---- phase 1: read A(mf0-3) + B(nf0-1); MFMA (mf0-3 x nf0-1)
#pragma unroll
    for (int mf = 0; mf < 4; ++mf) {
      const unsigned short* r = Ab + (wm * 128 + mf * 16 + cc) * 64;
      areg[mf][0] = *(const bf16x8*)(r + sw0);
      areg[mf][1] = *(const bf16x8*)(r + sw1);
    }
#pragma unroll
    for (int nf = 0; nf < 2; ++nf) {
      const unsigned short* r = Bb + (wn * 64 + nf * 16 + cc) * 64;
      breg[nf][0] = *(const bf16x8*)(r + sw0);
      breg[nf][1] = *(const bf16x8*)(r + sw1);
    }
    __builtin_amdgcn_s_barrier();
    asm volatile("s_waitcnt lgkmcnt(0)" ::: "memory");
    __builtin_amdgcn_s_setprio(1);
#pragma unroll
    for (int mf = 0; mf < 4; ++mf)
#pragma unroll
      for (int nf = 0; nf < 2; ++nf) {
        acc[mf][nf] = MF(areg[mf][0], breg[nf][0], acc[mf][nf]);
        acc[mf][nf] = MF(areg[mf][1], breg[nf][1], acc[mf][nf]);
      }
    __builtin_amdgcn_s_setprio(0);
    __builtin_amdgcn_s_barrier();

    // ---- phase 2: read B(nf2-3); MFMA (mf0-3 x nf2-3)
#pragma unroll
    for (int nf = 2; nf < 4; ++nf) {
      const unsigned short* r = Bb + (wn * 64 + nf * 16 + cc) * 64;
      breg[nf][0] = *(const bf16x8*)(r + sw0);
      breg[nf][1] = *(const bf16x8*)(r + sw1);
    }
    __builtin_amdgcn_s_barrier();
    asm volatile("s_waitcnt lgkmcnt(0)" ::: "memory");
    __builtin_amdgcn_s_setprio(1);
#pragma unroll
    for (int mf = 0; mf < 4; ++mf)
#pragma unroll
      for (int nf = 2; nf < 4; ++nf) {
        acc[mf][nf] = MF(areg[mf][0], breg[nf][0], acc[mf][nf]);
        acc[mf][nf] = MF(areg[mf][1], breg[nf][1], acc[mf][nf]);
      }
    __builtin_amdgcn_s_setprio(0);
    __builtin_amdgcn_s_barrier();   // all B-LDS reads of tile kt complete past here

    // ---- phase 3: read A(mf4-7); stage B(t+2) into buf p; MFMA (mf4-7 x nf2-3)
#pragma unroll
    for (int mf = 0; mf < 4; ++mf) {
      const unsigned short* r = Ab + (wm * 128 + (mf + 4) * 16 + cc) * 64;
      areg[mf][0] = *(const bf16x8*)(r + sw0);
      areg[mf][1] = *(const bf16x8*)(r + sw1);
    }
    stageB(p, ts);
    __builtin_amdgcn_s_barrier();
    asm volatile("s_waitcnt lgkmcnt(0)" ::: "memory");
    __builtin_amdgcn_s_setprio(1);
#pragma unroll
    for (int mf = 0; mf < 4; ++mf)
#pragma unroll
      for (int nf = 2; nf < 4; ++nf) {
        acc[mf + 4][nf] = MF(areg[mf][0], breg[nf][0], acc[mf + 4][nf]);
        acc[mf + 4][nf] = MF(areg[mf][1], breg[nf][1], acc[mf + 4][nf]);
      }
    __builtin_amdgcn_s_setprio(0);
    __builtin_amdgcn_s_barrier();   // all A-LDS reads of tile kt complete past here

    // ---- phase 4: stage A(t+2); vmcnt(8) (tile kt+1 landed); MFMA (mf4-7 x nf0-1)
    stageA(p, ts);
    asm volatile("s_waitcnt vmcnt(8)" ::: "memory");
    __builtin_amdgcn_s_setprio(1);
#pragma unroll
    for (int mf = 0; mf < 4; ++mf)
#pragma unroll
      for (int nf = 0; nf < 2; ++nf) {
        acc[mf + 4][nf] = MF(areg[mf][0], breg[nf][0], acc[mf + 4][nf]);
        acc[mf + 4][nf] = MF(areg[mf][1], breg[nf][1], acc[mf + 4][nf]);
      }
    __builtin_amdgcn_s_setprio(0);
    __builtin_amdgcn_s_barrier();
  }

  asm volatile("s_waitcnt vmcnt(0)" ::: "memory");   // drain clamped tail stages before LDS reuse
  __builtin_amdgcn_s_barrier();

  if (G == 1) {
    // ---- epilogue: v3 waves (wn>=2) -> LDS (f32, XOR-swizzled rows) -> v1 waves fuse silu ----
    float* fl = (float*)lds;   // 4 slots x (64 cols x 128 rows) f32 = 128 KiB
    if (wn >= 2) {
      const int slot = wm * 2 + (wn - 2);
      float* base = fl + slot * 8192;
#pragma unroll
      for (int mf = 0; mf < 8; ++mf)
#pragma unroll
        for (int nf = 0; nf < 4; ++nf)
          *(f32x4*)(base + (nf * 16 + cc) * 128 + ((mf * 16 + hi * 4) ^ ((cc & 7) << 2))) = acc[mf][nf];
    }
    __builtin_amdgcn_s_barrier();
    if (wn < 2) {
      const int slot = wm * 2 + wn;
      const float* base = fl + slot * 8192;
#pragma unroll
      for (int mf = 0; mf < 8; ++mf) {
        int rl = wm * 128 + mf * 16 + hi * 4;
#pragma unroll
        for (int nf = 0; nf < 4; ++nf) {
          f32x4 v3 = *(const f32x4*)(base + (nf * 16 + cc) * 128 + ((mf * 16 + hi * 4) ^ ((cc & 7) << 2)));
          int col = nb * 128 + wn * 64 + nf * 16 + cc;
#pragma unroll
          for (int r = 0; r < 4; ++r) {
            int row = rl + r;
            if (m0 + row < cnt) {
              float v1 = acc[mf][nf][r];
              float h = v1 / (1.0f + __expf(-v1)) * v3[r];
              hid_out[(size_t)(off + m0 + row) * KHID + col] = f2bf(h);
            }
          }
        }
      }
    }
  } else {
    // ---- epilogue: scale by routing weight, atomic accumulate into out ----
#pragma unroll
    for (int mf = 0; mf < 8; ++mf) {
      int rlb = wm * 128 + mf * 16 + hi * 4;
#pragma unroll
      for (int r = 0; r < 4; ++r) {
        int row = rlb + r;
        if (m0 + row < cnt) {
          int prow = off + m0 + row;
          int tok = ptok[prow];
          float w = prw[prow];
          float* op = out + (size_t)tok * KDIM + nb * 256 + wn * 64;
#pragma unroll
          for (int nf = 0; nf < 4; ++nf)
            unsafeAtomicAdd(&op[nf * 16 + cc], acc[mf][nf][r] * w);
        }
      }
    }
  }
}

extern "C" void kernel_launch(void* const* d_in, const int* in_sizes, int n_in,
                              void* d_out, int out_size, void* d_ws, size_t ws_size,
                              hipStream_t stream) {
  const float* x    = (const float*)d_in[0];
  const float* rwgt = (const float*)d_in[1];
  const float* w1   = (const float*)d_in[2];
  const float* w3   = (const float*)d_in[3];
  const float* w2   = (const float*)d_in[4];
  float* out = (float*)d_out;

  char* ws = (char*)d_ws;
  const size_t OFF_META = 0;
  const size_t OFF_SEL  = 512;
  const size_t OFF_RWT  = OFF_SEL  + (size_t)NPAIR * 4;
  const size_t OFF_PTOK = OFF_RWT  + (size_t)NPAIR * 4;
  const size_t OFF_PRW  = OFF_PTOK + (size_t)NPAIR * 4;
  const size_t OFF_XB   = OFF_PRW  + (size_t)NPAIR * 4;                 // 512-aligned
  const size_t OFF_W1B  = OFF_XB   + (size_t)TTOK * KDIM * 2;
  const size_t OFF_W3B  = OFF_W1B  + (size_t)NEXP * KHID * KDIM * 2;
  const size_t OFF_W2B  = OFF_W3B  + (size_t)NEXP * KHID * KDIM * 2;
  const size_t OFF_HID  = OFF_W2B  + (size_t)NEXP * KDIM * KHID * 2;
  const size_t END      = OFF_HID  + (size_t)(NPAIR + 256) * KHID * 2;  // ~177 MiB
  if (ws_size < END) return;  // ws too small: fail safely (visible as absmax fail)

  int*   meta = (int*)(ws + OFF_META);
  int*   sel  = (int*)(ws + OFF_SEL);
  float* rwt  = (float*)(ws + OFF_RWT);
  int*   ptok = (int*)(ws + OFF_PTOK);
  float* prw  = (float*)(ws + OFF_PRW);
  unsigned short* xb  = (unsigned short*)(ws + OFF_XB);
  unsigned short* w1b = (unsigned short*)(ws + OFF_W1B);
  unsigned short* w3b = (unsigned short*)(ws + OFF_W3B);
  unsigned short* w2b = (unsigned short*)(ws + OFF_W2B);
  unsigned short* hid = (unsigned short*)(ws + OFF_HID);

  hipMemsetAsync(d_out, 0, (size_t)out_size * 4, stream);
  hipMemsetAsync(meta, 0, 512, stream);

  convert_kernel<<<28672, 256, 0, stream>>>(
      (const float4*)x, (const float4*)w1, (const float4*)w3, (const float4*)w2,
      (uint4*)xb, (uint4*)w1b, (uint4*)w3b, (uint4*)w2b);
  router_kernel<<<TTOK / 4, 256, 0, stream>>>(x, rwgt, out, sel, rwt, meta);
  scan_kernel<<<1, 64, 0, stream>>>(meta);
  fill_kernel<<<NPAIR / 256, 256, 0, stream>>>(sel, rwt, meta, ptok, prw);
  gemm8p_kernel<1><<<dim3(KHID / 128, 32, NEXP), 512, 0, stream>>>(
      xb, w1b, w3b, meta, ptok, nullptr, hid, nullptr);
  gemm8p_kernel<2><<<dim3(KDIM / 256, 32, NEXP), 512, 0, stream>>>(
      hid, w2b, nullptr, meta, ptok, prw, nullptr, out);
}

// Round 3
// 652.833 us; speedup vs baseline: 1.0456x; 1.0426x over previous
//
#include <hip/hip_runtime.h>
#include <hip/hip_bf16.h>
#include <stdint.h>

#define TTOK 8192          // B*N tokens
#define KDIM 1024
#define KHID 2048
#define NEXP 8
#define NPAIR 16384        // TTOK * top2

typedef __attribute__((ext_vector_type(8))) short bf16x8;
typedef __attribute__((ext_vector_type(4))) float f32x4;

__device__ __forceinline__ unsigned short f2bf(float f) {
  union { float f; uint32_t u; } v; v.f = f;
  uint32_t r = (v.u + 0x7FFFu + ((v.u >> 16) & 1u)) >> 16;
  return (unsigned short)r;
}
__device__ __forceinline__ uint32_t pack2(float a, float b) {
  return (uint32_t)f2bf(a) | ((uint32_t)f2bf(b) << 16);
}

// async global->LDS, 16B per lane; LDS dest is wave-uniform base + lane*16
__device__ __forceinline__ void llds16(const void* g, void* l) {
  __builtin_amdgcn_global_load_lds(
      (const __attribute__((address_space(1))) uint32_t*)g,
      (__attribute__((address_space(3))) uint32_t*)l, 16, 0, 0);
}

__device__ __forceinline__ f32x4 MF(bf16x8 a, bf16x8 b, f32x4 c) {
  return __builtin_amdgcn_mfma_f32_16x16x32_bf16(a, b, c, 0, 0, 0);
}

// ---------------- fp32 -> bf16 conversion of x, w1, w3, w2 ----------------
__global__ __launch_bounds__(256) void convert_kernel(
    const float4* __restrict__ x, const float4* __restrict__ w1,
    const float4* __restrict__ w3, const float4* __restrict__ w2,
    uint4* __restrict__ xb, uint4* __restrict__ w1b,
    uint4* __restrict__ w3b, uint4* __restrict__ w2b) {
  size_t u = (size_t)blockIdx.x * 256 + threadIdx.x;   // unit = 8 floats
  const size_t NX = (size_t)TTOK * KDIM / 8;           // 1048576
  const size_t NW = (size_t)NEXP * KHID * KDIM / 8;    // 2097152
  const float4* src; uint4* dst; size_t i;
  if (u < NX)               { src = x;  dst = xb;  i = u; }
  else if (u < NX + NW)     { src = w1; dst = w1b; i = u - NX; }
  else if (u < NX + 2 * NW) { src = w3; dst = w3b; i = u - NX - NW; }
  else if (u < NX + 3 * NW) { src = w2; dst = w2b; i = u - NX - 2 * NW; }
  else return;
  float4 a = src[2 * i], b = src[2 * i + 1];
  uint4 r;
  r.x = pack2(a.x, a.y); r.y = pack2(a.z, a.w);
  r.z = pack2(b.x, b.y); r.w = pack2(b.z, b.w);
  dst[i] = r;
}

// ---------------- router: fp64 logits, top-2, softmax ----------------
// meta layout (ints): [0..7] counts, [8..16] offsets, [17..24] cursors
__global__ __launch_bounds__(256) void router_kernel(
    const float* __restrict__ x, const float* __restrict__ rwgt,
    float* __restrict__ dout, int* __restrict__ sel, float* __restrict__ rwt,
    int* __restrict__ meta) {
  __shared__ float rl[NEXP * KDIM];   // 32 KB
  for (int i = threadIdx.x; i < NEXP * KDIM / 4; i += 256)
    ((float4*)rl)[i] = ((const float4*)rwgt)[i];
  __syncthreads();
  int wid = threadIdx.x >> 6, lane = threadIdx.x & 63;
  int t = blockIdx.x * 4 + wid;
  const float* xt = x + (size_t)t * KDIM;
  float xf[16];
#pragma unroll
  for (int i = 0; i < 16; i++) xf[i] = xt[lane + 64 * i];
  double acc[NEXP];
#pragma unroll
  for (int e = 0; e < NEXP; e++) {
    double a = 0.0;
    const float* re = rl + e * KDIM;
#pragma unroll
    for (int i = 0; i < 16; i++) a += (double)xf[i] * (double)re[lane + 64 * i];
#pragma unroll
    for (int off = 32; off > 0; off >>= 1) a += __shfl_xor(a, off);
    acc[e] = a;
  }
  if (lane == 0) {
    int e1 = 0; double l1 = acc[0];
#pragma unroll
    for (int e = 1; e < NEXP; e++) if (acc[e] > l1) { l1 = acc[e]; e1 = e; }
    int e2 = (e1 == 0) ? 1 : 0; double l2 = acc[e2];
#pragma unroll
    for (int e = 0; e < NEXP; e++)
      if (e != e1 && e != e2 && acc[e] > l2) { l2 = acc[e]; e2 = e; }
    double p2 = exp(l2 - l1);
    double s = 1.0 + p2;
    float wa = (float)(1.0 / s), wb = (float)(p2 / s);
    float* rw_out = dout + (size_t)TTOK * KDIM;
    float* sel_out = rw_out + (size_t)TTOK * 2;
    rw_out[2 * t] = wa;  rw_out[2 * t + 1] = wb;
    sel_out[2 * t] = (float)e1;  sel_out[2 * t + 1] = (float)e2;
    sel[2 * t] = e1;  sel[2 * t + 1] = e2;
    rwt[2 * t] = wa;  rwt[2 * t + 1] = wb;
    atomicAdd(&meta[e1], 1);  atomicAdd(&meta[e2], 1);
  }
}

__global__ void scan_kernel(int* meta) {
  if (threadIdx.x == 0 && blockIdx.x == 0) {
    int o = 0;
#pragma unroll
    for (int e = 0; e < NEXP; e++) { meta[8 + e] = o; o += meta[e]; meta[17 + e] = 0; }
    meta[16] = o;
  }
}

__global__ __launch_bounds__(256) void fill_kernel(
    const int* __restrict__ sel, const float* __restrict__ rwt,
    int* __restrict__ meta, int* __restrict__ ptok, float* __restrict__ prw) {
  int i = blockIdx.x * 256 + threadIdx.x;   // pair index = t*2 + k
  if (i >= NPAIR) return;
  int e = sel[i];
  int slot = atomicAdd(&meta[17 + e], 1);
  int row = meta[8 + e] + slot;
  ptok[row] = i >> 1;
  prw[row] = rwt[i];
}

// ---------------- 256-row / BK=64 / 8-wave / double-buffered 4-phase GEMM ----------------
// G=1: hidden = silu(Xg @ w1^T) * (Xg @ w3^T). Each wave's 64 B-rows = 32 w1-rows + 32
//      w3-rows of the SAME 32 hid cols -> SiLU is wave-local (no LDS exchange).
// G=2: out[tok] += prw * (hidden @ w2^T), atomic accumulate.
template<int G>
__device__ __forceinline__ void gemm_body(
    const unsigned short* __restrict__ A,
    const unsigned short* __restrict__ B0,
    const unsigned short* __restrict__ B1,
    const int* __restrict__ meta,
    const int* __restrict__ ptok,
    const float* __restrict__ prw,
    unsigned short* __restrict__ hid_out,
    float* __restrict__ out) {
  constexpr int KK = (G == 1) ? KDIM : KHID;   // inner dim (A and B row stride)
  constexpr int NT = KK / 64;

  // ---- XCD-locality remap: XCD = linear%8 (m09); give each XCD a compact
  //      per-expert chunk so its staging working set fits the 4 MiB L2. ----
  int e, mt, nb;
  if (G == 1) {
    // grid (16,32,8): per expert per XCD -> 4mt x 4nb chunk (2MB A + 2MB B)
    int lin = blockIdx.x + 16 * blockIdx.y + 512 * blockIdx.z;
    int x = lin & 7, j = lin >> 3;
    e = j >> 6; int jj = j & 63;
    nb = 4 * (x & 3) + (jj & 3);
    mt = 2 * (jj >> 2) + (x >> 2);
  } else {
    // grid (4,32,8): per expert per XCD -> 2mt x 2nb chunk (2MB A + 2MB B)
    int lin = blockIdx.x + 4 * blockIdx.y + 128 * blockIdx.z;
    int x = lin & 7, j = lin >> 3;
    e = j >> 4; int jj = j & 15;
    nb = 2 * (x & 1) + (jj & 1);
    mt = 4 * (jj >> 1) + (x >> 1);
  }

  const int cnt = meta[e];
  const int m0 = mt * 256;
  if (m0 >= cnt) return;
  const int off = meta[8 + e];

  // staging: [buf(2)][A/B(2)][256*64] bf16 = 128 KiB
  __shared__ unsigned short lds[2 * 2 * 16384];

  const int tid = threadIdx.x;
  const int wid = tid >> 6, lane = tid & 63;
  const int wm = wid >> 2, wn = wid & 3;
  const int cc = lane & 15, hi = lane >> 4;

  // ---- staging source setup (pre-swizzled global column: col8_g = col8 ^ (row&7)) ----
  const int srow = tid >> 3;                         // 0..63: row within 64-row chunk
  const int scol = (((tid & 7) ^ (srow & 7)) << 3);  // element offset
  const unsigned short* asrc[4];
  const unsigned short* bsrc[4];
#pragma unroll
  for (int s = 0; s < 4; ++s) {
    int ar = m0 + s * 64 + srow;
    if (ar > cnt - 1) ar = cnt - 1;
    if (G == 1) {
      int tok = ptok[off + ar];
      asrc[s] = A + (size_t)tok * KK + scol;
    } else {
      asrc[s] = A + (size_t)(off + ar) * KK + scol;
    }
    if (G == 1) {
      // B-tile row r = s*64+srow: group s (wave s), sub=srow; sub<32 -> w1, else w3,
      // both at hid col block nb*128 + s*32 + (sub&31)
      int brow = nb * 128 + s * 32 + (srow & 31);
      const unsigned short* bb = (srow < 32) ? B0 : B1;
      bsrc[s] = bb + ((size_t)e * KHID + brow) * KK + scol;
    } else {
      int brow = nb * 256 + s * 64 + srow;
      bsrc[s] = B0 + ((size_t)e * KDIM + brow) * KK + scol;
    }
  }

  auto stageA = [&](int buf, int kt) {
    unsigned short* d = lds + buf * 32768;
#pragma unroll
    for (int s = 0; s < 4; ++s)
      llds16(asrc[s] + kt * 64, d + (s * 64 + wid * 8) * 64);
  };
  auto stageB = [&](int buf, int kt) {
    unsigned short* d = lds + buf * 32768 + 16384;
#pragma unroll
    for (int s = 0; s < 4; ++s)
      llds16(bsrc[s] + kt * 64, d + (s * 64 + wid * 8) * 64);
  };

  // ---- swizzled LDS read offsets: col8 = (ks*4+hi) ^ (row&7); row&7 == cc&7 always ----
  const int sw0 = ((hi) ^ (cc & 7)) << 3;            // ks=0, elements
  const int sw1 = ((4 + hi) ^ (cc & 7)) << 3;        // ks=1

  f32x4 acc[8][4] = {};
  bf16x8 areg[4][2], breg[4][2];

  // prologue: stage tiles 0 and 1
  stageA(0, 0); stageB(0, 0); stageA(1, 1); stageB(1, 1);
  asm volatile("s_waitcnt vmcnt(8)" ::: "memory");   // tile 0 landed
  __builtin_amdgcn_s_barrier();

#pragma unroll 1
  for (int kt = 0; kt < NT; ++kt) {
    const int p = kt & 1;
    const int ts = (kt + 2 < NT) ? kt + 2 : NT - 1;  // clamp keeps vmcnt static
    const unsigned short* Ab = lds + p * 32768;
    const unsigned short* Bb = Ab + 16384;

    // ---- phase 1: read A(mf0-3) + B(nf0-1); MFMA (mf0-3 x nf0-1)
#pragma unroll
    for (int mf = 0; mf < 4; ++mf) {
      const unsigned short* r = Ab + (wm * 128 + mf * 16 + cc) * 64;
      areg[mf][0] = *(const bf16x8*)(r + sw0);
      areg[mf][1] = *(const bf16x8*)(r + sw1);
    }
#pragma unroll
    for (int nf = 0; nf < 2; ++nf) {
      const unsigned short* r = Bb + (wn * 64 + nf * 16 + cc) * 64;
      breg[nf][0] = *(const bf16x8*)(r + sw0);
      breg[nf][1] = *(const bf16x8*)(r + sw1);
    }
    __builtin_amdgcn_s_barrier();
    asm volatile("s_waitcnt lgkmcnt(0)" ::: "memory");
    __builtin_amdgcn_s_setprio(1);
#pragma unroll
    for (int mf = 0; mf < 4; ++mf)
#pragma unroll
      for (int nf = 0; nf < 2; ++nf) {
        acc[mf][nf] = MF(areg[mf][0], breg[nf][0], acc[mf][nf]);
        acc[mf][nf] = MF(areg[mf][1], breg[nf][1], acc[mf][nf]);
      }
    __builtin_amdgcn_s_setprio(0);
    __builtin_amdgcn_s_barrier();

    // ---- phase 2: read B(nf2-3); MFMA (mf0-3 x nf2-3)
#pragma unroll
    for (int nf = 2; nf < 4; ++nf) {
      const unsigned short* r = Bb + (wn * 64 + nf * 16 + cc) * 64;
      breg[nf][0] = *(const bf16x8*)(r + sw0);
      breg[nf][1] = *(const bf16x8*)(r + sw1);
    }
    __builtin_amdgcn_s_barrier();
    asm volatile("s_waitcnt lgkmcnt(0)" ::: "memory");
    __builtin_amdgcn_s_setprio(1);
#pragma unroll
    for (int mf = 0; mf < 4; ++mf)
#pragma unroll
      for (int nf = 2; nf < 4; ++nf) {
        acc[mf][nf] = MF(areg[mf][0], breg[nf][0], acc[mf][nf]);
        acc[mf][nf] = MF(areg[mf][1], breg[nf][1], acc[mf][nf]);
      }
    __builtin_amdgcn_s_setprio(0);
    __builtin_amdgcn_s_barrier();   // all B-LDS reads of tile kt complete past here

    // ---- phase 3: read A(mf4-7); stage B(t+2) into buf p; MFMA (mf4-7 x nf2-3)
#pragma unroll
    for (int mf = 0; mf < 4; ++mf) {
      const unsigned short* r = Ab + (wm * 128 + (mf + 4) * 16 + cc) * 64;
      areg[mf][0] = *(const bf16x8*)(r + sw0);
      areg[mf][1] = *(const bf16x8*)(r + sw1);
    }
    stageB(p, ts);
    __builtin_amdgcn_s_barrier();
    asm volatile("s_waitcnt lgkmcnt(0)" ::: "memory");
    __builtin_amdgcn_s_setprio(1);
#pragma unroll
    for (int mf = 0; mf < 4; ++mf)
#pragma unroll
      for (int nf = 2; nf < 4; ++nf) {
        acc[mf + 4][nf] = MF(areg[mf][0], breg[nf][0], acc[mf + 4][nf]);
        acc[mf + 4][nf] = MF(areg[mf][1], breg[nf][1], acc[mf + 4][nf]);
      }
    __builtin_amdgcn_s_setprio(0);
    __builtin_amdgcn_s_barrier();   // all A-LDS reads of tile kt complete past here

    // ---- phase 4: stage A(t+2); vmcnt(8) (tile kt+1 landed); MFMA (mf4-7 x nf0-1)
    stageA(p, ts);
    asm volatile("s_waitcnt vmcnt(8)" ::: "memory");
    __builtin_amdgcn_s_setprio(1);
#pragma unroll
    for (int mf = 0; mf < 4; ++mf)
#pragma unroll
      for (int nf = 0; nf < 2; ++nf) {
        acc[mf + 4][nf] = MF(areg[mf][0], breg[nf][0], acc[mf + 4][nf]);
        acc[mf + 4][nf] = MF(areg[mf][1], breg[nf][1], acc[mf + 4][nf]);
      }
    __builtin_amdgcn_s_setprio(0);
    __builtin_amdgcn_s_barrier();
  }

  asm volatile("s_waitcnt vmcnt(0)" ::: "memory");   // drain clamped tail stages

  if (G == 1) {
    // ---- epilogue: wave-local SiLU: v1 = acc[mf][cf], v3 = acc[mf][cf+2] ----
#pragma unroll
    for (int mf = 0; mf < 8; ++mf) {
      int rlb = wm * 128 + mf * 16 + hi * 4;
#pragma unroll
      for (int cf = 0; cf < 2; ++cf) {
        int col = nb * 128 + wn * 32 + cf * 16 + cc;
#pragma unroll
        for (int r = 0; r < 4; ++r) {
          int row = rlb + r;
          if (m0 + row < cnt) {
            float v1 = acc[mf][cf][r], v3 = acc[mf][cf + 2][r];
            float h = v1 / (1.0f + __expf(-v1)) * v3;
            hid_out[(size_t)(off + m0 + row) * KHID + col] = f2bf(h);
          }
        }
      }
    }
  } else {
    // ---- epilogue: scale by routing weight, atomic accumulate into out ----
#pragma unroll
    for (int mf = 0; mf < 8; ++mf) {
      int rlb = wm * 128 + mf * 16 + hi * 4;
#pragma unroll
      for (int r = 0; r < 4; ++r) {
        int row = rlb + r;
        if (m0 + row < cnt) {
          int prow = off + m0 + row;
          int tok = ptok[prow];
          float w = prw[prow];
          float* op = out + (size_t)tok * KDIM + nb * 256 + wn * 64;
#pragma unroll
          for (int nf = 0; nf < 4; ++nf)
            unsafeAtomicAdd(&op[nf * 16 + cc], acc[mf][nf][r] * w);
        }
      }
    }
  }
}

__global__ __launch_bounds__(512, 2) void gemm1_kernel(
    const unsigned short* __restrict__ A, const unsigned short* __restrict__ B0,
    const unsigned short* __restrict__ B1, const int* __restrict__ meta,
    const int* __restrict__ ptok, unsigned short* __restrict__ hid_out) {
  gemm_body<1>(A, B0, B1, meta, ptok, nullptr, hid_out, nullptr);
}

__global__ __launch_bounds__(512, 2) void gemm2_kernel(
    const unsigned short* __restrict__ A, const unsigned short* __restrict__ B0,
    const int* __restrict__ meta, const int* __restrict__ ptok,
    const float* __restrict__ prw, float* __restrict__ out) {
  gemm_body<2>(A, B0, nullptr, meta, ptok, prw, nullptr, out);
}

extern "C" void kernel_launch(void* const* d_in, const int* in_sizes, int n_in,
                              void* d_out, int out_size, void* d_ws, size_t ws_size,
                              hipStream_t stream) {
  const float* x    = (const float*)d_in[0];
  const float* rwgt = (const float*)d_in[1];
  const float* w1   = (const float*)d_in[2];
  const float* w3   = (const float*)d_in[3];
  const float* w2   = (const float*)d_in[4];
  float* out = (float*)d_out;

  char* ws = (char*)d_ws;
  const size_t OFF_META = 0;
  const size_t OFF_SEL  = 512;
  const size_t OFF_RWT  = OFF_SEL  + (size_t)NPAIR * 4;
  const size_t OFF_PTOK = OFF_RWT  + (size_t)NPAIR * 4;
  const size_t OFF_PRW  = OFF_PTOK + (size_t)NPAIR * 4;
  const size_t OFF_XB   = OFF_PRW  + (size_t)NPAIR * 4;                 // 512-aligned
  const size_t OFF_W1B  = OFF_XB   + (size_t)TTOK * KDIM * 2;
  const size_t OFF_W3B  = OFF_W1B  + (size_t)NEXP * KHID * KDIM * 2;
  const size_t OFF_W2B  = OFF_W3B  + (size_t)NEXP * KHID * KDIM * 2;
  const size_t OFF_HID  = OFF_W2B  + (size_t)NEXP * KDIM * KHID * 2;
  const size_t END      = OFF_HID  + (size_t)(NPAIR + 256) * KHID * 2;  // ~177 MiB
  if (ws_size < END) return;  // ws too small: fail safely (visible as absmax fail)

  int*   meta = (int*)(ws + OFF_META);
  int*   sel  = (int*)(ws + OFF_SEL);
  float* rwt  = (float*)(ws + OFF_RWT);
  int*   ptok = (int*)(ws + OFF_PTOK);
  float* prw  = (float*)(ws + OFF_PRW);
  unsigned short* xb  = (unsigned short*)(ws + OFF_XB);
  unsigned short* w1b = (unsigned short*)(ws + OFF_W1B);
  unsigned short* w3b = (unsigned short*)(ws + OFF_W3B);
  unsigned short* w2b = (unsigned short*)(ws + OFF_W2B);
  unsigned short* hid = (unsigned short*)(ws + OFF_HID);

  hipMemsetAsync(d_out, 0, (size_t)out_size * 4, stream);
  hipMemsetAsync(meta, 0, 512, stream);

  convert_kernel<<<28672, 256, 0, stream>>>(
      (const float4*)x, (const float4*)w1, (const float4*)w3, (const float4*)w2,
      (uint4*)xb, (uint4*)w1b, (uint4*)w3b, (uint4*)w2b);
  router_kernel<<<TTOK / 4, 256, 0, stream>>>(x, rwgt, out, sel, rwt, meta);
  scan_kernel<<<1, 64, 0, stream>>>(meta);
  fill_kernel<<<NPAIR / 256, 256, 0, stream>>>(sel, rwt, meta, ptok, prw);
  gemm1_kernel<<<dim3(16, 32, NEXP), 512, 0, stream>>>(xb, w1b, w3b, meta, ptok, hid);
  gemm2_kernel<<<dim3(4, 32, NEXP), 512, 0, stream>>>(hid, w2b, meta, ptok, prw, out);
}

// Round 4
// 426.781 us; speedup vs baseline: 1.5994x; 1.5297x over previous
//
#include <hip/hip_runtime.h>
#include <hip/hip_bf16.h>
#include <stdint.h>

#define TTOK 8192          // B*N tokens
#define KDIM 1024
#define KHID 2048
#define NEXP 8
#define NPAIR 16384        // TTOK * top2
#define RBLK 512           // router blocks (16 tokens each)

typedef __attribute__((ext_vector_type(8))) short bf16x8;
typedef __attribute__((ext_vector_type(4))) float f32x4;

__device__ __forceinline__ unsigned short f2bf(float f) {
  union { float f; uint32_t u; } v; v.f = f;
  uint32_t r = (v.u + 0x7FFFu + ((v.u >> 16) & 1u)) >> 16;
  return (unsigned short)r;
}
__device__ __forceinline__ uint32_t pack2(float a, float b) {
  return (uint32_t)f2bf(a) | ((uint32_t)f2bf(b) << 16);
}

// async global->LDS, 16B per lane; LDS dest is wave-uniform base + lane*16
__device__ __forceinline__ void llds16(const void* g, void* l) {
  __builtin_amdgcn_global_load_lds(
      (const __attribute__((address_space(1))) uint32_t*)g,
      (__attribute__((address_space(3))) uint32_t*)l, 16, 0, 0);
}

__device__ __forceinline__ f32x4 MF(bf16x8 a, bf16x8 b, f32x4 c) {
  return __builtin_amdgcn_mfma_f32_16x16x32_bf16(a, b, c, 0, 0, 0);
}

// ---------------- fp32 -> bf16 conversion of x, w1, w3, w2 ----------------
__global__ __launch_bounds__(256) void convert_kernel(
    const float4* __restrict__ x, const float4* __restrict__ w1,
    const float4* __restrict__ w3, const float4* __restrict__ w2,
    uint4* __restrict__ xb, uint4* __restrict__ w1b,
    uint4* __restrict__ w3b, uint4* __restrict__ w2b) {
  size_t u = (size_t)blockIdx.x * 256 + threadIdx.x;   // unit = 8 floats
  const size_t NX = (size_t)TTOK * KDIM / 8;           // 1048576
  const size_t NW = (size_t)NEXP * KHID * KDIM / 8;    // 2097152
  const float4* src; uint4* dst; size_t i;
  if (u < NX)               { src = x;  dst = xb;  i = u; }
  else if (u < NX + NW)     { src = w1; dst = w1b; i = u - NX; }
  else if (u < NX + 2 * NW) { src = w3; dst = w3b; i = u - NX - NW; }
  else if (u < NX + 3 * NW) { src = w2; dst = w2b; i = u - NX - 2 * NW; }
  else return;
  float4 a = src[2 * i], b = src[2 * i + 1];
  uint4 r;
  r.x = pack2(a.x, a.y); r.y = pack2(a.z, a.w);
  r.z = pack2(b.x, b.y); r.w = pack2(b.z, b.w);
  dst[i] = r;
}

// ---------------- router: fp64 logits, top-2, softmax; NO global atomics ----------------
// 512 blocks x 256 thr; each wave handles 4 tokens. Per-block LDS histogram ->
// block-local slot per pair + per-block expert counts (scanned by scan_kernel).
__global__ __launch_bounds__(256) void router_kernel(
    const float* __restrict__ x, const float* __restrict__ rwgt,
    float* __restrict__ dout, int* __restrict__ sel, float* __restrict__ rwt,
    int* __restrict__ lslot, int* __restrict__ blkcnt) {
  __shared__ float rl[NEXP * KDIM];   // 32 KB
  __shared__ int lcnt[NEXP];
  for (int i = threadIdx.x; i < NEXP * KDIM / 4; i += 256)
    ((float4*)rl)[i] = ((const float4*)rwgt)[i];
  if (threadIdx.x < NEXP) lcnt[threadIdx.x] = 0;
  __syncthreads();
  int wid = threadIdx.x >> 6, lane = threadIdx.x & 63;
#pragma unroll 1
  for (int tt = 0; tt < 4; ++tt) {
    int t = blockIdx.x * 16 + wid * 4 + tt;
    const float* xt = x + (size_t)t * KDIM;
    float xf[16];
#pragma unroll
    for (int i = 0; i < 16; i++) xf[i] = xt[lane + 64 * i];
    double acc[NEXP];
#pragma unroll
    for (int e = 0; e < NEXP; e++) {
      double a = 0.0;
      const float* re = rl + e * KDIM;
#pragma unroll
      for (int i = 0; i < 16; i++) a += (double)xf[i] * (double)re[lane + 64 * i];
#pragma unroll
      for (int off = 32; off > 0; off >>= 1) a += __shfl_xor(a, off);
      acc[e] = a;
    }
    if (lane == 0) {
      int e1 = 0; double l1 = acc[0];
#pragma unroll
      for (int e = 1; e < NEXP; e++) if (acc[e] > l1) { l1 = acc[e]; e1 = e; }
      int e2 = (e1 == 0) ? 1 : 0; double l2 = acc[e2];
#pragma unroll
      for (int e = 0; e < NEXP; e++)
        if (e != e1 && e != e2 && acc[e] > l2) { l2 = acc[e]; e2 = e; }
      double p2 = exp(l2 - l1);
      double s = 1.0 + p2;
      float wa = (float)(1.0 / s), wb = (float)(p2 / s);
      float* rw_out = dout + (size_t)TTOK * KDIM;
      float* sel_out = rw_out + (size_t)TTOK * 2;
      rw_out[2 * t] = wa;  rw_out[2 * t + 1] = wb;
      sel_out[2 * t] = (float)e1;  sel_out[2 * t + 1] = (float)e2;
      sel[2 * t] = e1;  sel[2 * t + 1] = e2;
      rwt[2 * t] = wa;  rwt[2 * t + 1] = wb;
      int s1 = atomicAdd(&lcnt[e1], 1);     // LDS atomic: block-local, fast
      int s2 = atomicAdd(&lcnt[e2], 1);
      lslot[2 * t] = s1;  lslot[2 * t + 1] = s2;
    }
  }
  __syncthreads();
  if (threadIdx.x < NEXP) blkcnt[blockIdx.x * NEXP + threadIdx.x] = lcnt[threadIdx.x];
}

// ---------------- scan: blkcnt[512][8] -> per-block bases (in place) + meta ----------------
__global__ void scan_kernel(int* __restrict__ blkcnt, int* __restrict__ meta) {
  __shared__ int csum[64];
  const int tid = threadIdx.x;          // 64 threads
  const int e = tid & 7, c = tid >> 3;  // 8 chunks x 64 blocks
  int run = 0;
#pragma unroll 1
  for (int b = c * 64; b < c * 64 + 64; ++b) {
    int v = blkcnt[b * 8 + e];
    blkcnt[b * 8 + e] = run;            // local prefix within chunk
    run += v;
  }
  csum[c * 8 + e] = run;
  __syncthreads();
  if (tid < 8) {
    int tot = 0;
#pragma unroll
    for (int cc = 0; cc < 8; ++cc) { int v = csum[cc * 8 + tid]; csum[cc * 8 + tid] = tot; tot += v; }
    meta[tid] = tot;
  }
  __syncthreads();
  if (tid == 0) {
    int o = 0;
#pragma unroll
    for (int ee = 0; ee < 8; ++ee) { meta[8 + ee] = o; o += meta[ee]; }
    meta[16] = o;
  }
  const int base = csum[c * 8 + e];
#pragma unroll 1
  for (int b = c * 64; b < c * 64 + 64; ++b) blkcnt[b * 8 + e] += base;
}

// ---------------- fill: pure gather, no atomics ----------------
__global__ __launch_bounds__(256) void fill_kernel(
    const int* __restrict__ sel, const float* __restrict__ rwt,
    const int* __restrict__ lslot, const int* __restrict__ blkcnt,
    const int* __restrict__ meta, int* __restrict__ ptok, float* __restrict__ prw) {
  int i = blockIdx.x * 256 + threadIdx.x;   // pair index = t*2 + k
  if (i >= NPAIR) return;
  int e = sel[i];
  int t = i >> 1;
  int blk = t >> 4;                          // 16 tokens per router block
  int row = meta[8 + e] + blkcnt[blk * 8 + e] + lslot[i];
  ptok[row] = t;
  prw[row] = rwt[i];
}

// ---------------- 256-row / BK=64 / 8-wave / double-buffered 4-phase GEMM ----------------
// G=1: hidden = silu(Xg @ w1^T) * (Xg @ w3^T). Each wave's 64 B-rows = 32 w1-rows + 32
//      w3-rows of the SAME 32 hid cols -> SiLU is wave-local (no LDS exchange).
// G=2: out[tok] += prw * (hidden @ w2^T), atomic accumulate.
template<int G>
__device__ __forceinline__ void gemm_body(
    const unsigned short* __restrict__ A,
    const unsigned short* __restrict__ B0,
    const unsigned short* __restrict__ B1,
    const int* __restrict__ meta,
    const int* __restrict__ ptok,
    const float* __restrict__ prw,
    unsigned short* __restrict__ hid_out,
    float* __restrict__ out) {
  constexpr int KK = (G == 1) ? KDIM : KHID;   // inner dim (A and B row stride)
  constexpr int NT = KK / 64;

  // ---- XCD-locality remap: XCD = linear%8 (m09); give each XCD a compact
  //      per-expert chunk so its staging working set fits the 4 MiB L2. ----
  int e, mt, nb;
  if (G == 1) {
    // grid (16,32,8): per expert per XCD -> 4mt x 4nb chunk (2MB A + 2MB B)
    int lin = blockIdx.x + 16 * blockIdx.y + 512 * blockIdx.z;
    int x = lin & 7, j = lin >> 3;
    e = j >> 6; int jj = j & 63;
    nb = 4 * (x & 3) + (jj & 3);
    mt = 2 * (jj >> 2) + (x >> 2);
  } else {
    // grid (4,32,8): per expert per XCD -> 2mt x 2nb chunk (2MB A + 2MB B)
    int lin = blockIdx.x + 4 * blockIdx.y + 128 * blockIdx.z;
    int x = lin & 7, j = lin >> 3;
    e = j >> 4; int jj = j & 15;
    nb = 2 * (x & 1) + (jj & 1);
    mt = 4 * (jj >> 1) + (x >> 1);
  }

  const int cnt = meta[e];
  const int m0 = mt * 256;
  if (m0 >= cnt) return;
  const int off = meta[8 + e];

  // staging: [buf(2)][A/B(2)][256*64] bf16 = 128 KiB
  __shared__ unsigned short lds[2 * 2 * 16384];

  const int tid = threadIdx.x;
  const int wid = tid >> 6, lane = tid & 63;
  const int wm = wid >> 2, wn = wid & 3;
  const int cc = lane & 15, hi = lane >> 4;

  // ---- staging source setup (pre-swizzled global column: col8_g = col8 ^ (row&7)) ----
  const int srow = tid >> 3;                         // 0..63: row within 64-row chunk
  const int scol = (((tid & 7) ^ (srow & 7)) << 3);  // element offset
  const unsigned short* asrc[4];
  const unsigned short* bsrc[4];
#pragma unroll
  for (int s = 0; s < 4; ++s) {
    int ar = m0 + s * 64 + srow;
    if (ar > cnt - 1) ar = cnt - 1;
    if (G == 1) {
      int tok = ptok[off + ar];
      asrc[s] = A + (size_t)tok * KK + scol;
    } else {
      asrc[s] = A + (size_t)(off + ar) * KK + scol;
    }
    if (G == 1) {
      // B-tile row r = s*64+srow: wave s; sub=srow; sub<32 -> w1, else w3,
      // both at hid col block nb*128 + s*32 + (sub&31)
      int brow = nb * 128 + s * 32 + (srow & 31);
      const unsigned short* bb = (srow < 32) ? B0 : B1;
      bsrc[s] = bb + ((size_t)e * KHID + brow) * KK + scol;
    } else {
      int brow = nb * 256 + s * 64 + srow;
      bsrc[s] = B0 + ((size_t)e * KDIM + brow) * KK + scol;
    }
  }

  auto stageA = [&](int buf, int kt) {
    unsigned short* d = lds + buf * 32768;
#pragma unroll
    for (int s = 0; s < 4; ++s)
      llds16(asrc[s] + kt * 64, d + (s * 64 + wid * 8) * 64);
  };
  auto stageB = [&](int buf, int kt) {
    unsigned short* d = lds + buf * 32768 + 16384;
#pragma unroll
    for (int s = 0; s < 4; ++s)
      llds16(bsrc[s] + kt * 64, d + (s * 64 + wid * 8) * 64);
  };

  // ---- swizzled LDS read offsets: col8 = (ks*4+hi) ^ (row&7); row&7 == cc&7 always ----
  const int sw0 = ((hi) ^ (cc & 7)) << 3;            // ks=0, elements
  const int sw1 = ((4 + hi) ^ (cc & 7)) << 3;        // ks=1

  f32x4 acc[8][4] = {};
  bf16x8 areg[4][2], breg[4][2];

  // prologue: stage tiles 0 and 1
  stageA(0, 0); stageB(0, 0); stageA(1, 1); stageB(1, 1);
  asm volatile("s_waitcnt vmcnt(8)" ::: "memory");   // tile 0 landed
  __builtin_amdgcn_s_barrier();

#pragma unroll 1
  for (int kt = 0; kt < NT; ++kt) {
    const int p = kt & 1;
    const int ts = (kt + 2 < NT) ? kt + 2 : NT - 1;  // clamp keeps vmcnt static
    const unsigned short* Ab = lds + p * 32768;
    const unsigned short* Bb = Ab + 16384;

    // ---- phase 1: read A(mf0-3) + B(nf0-1); MFMA (mf0-3 x nf0-1)
#pragma unroll
    for (int mf = 0; mf < 4; ++mf) {
      const unsigned short* r = Ab + (wm * 128 + mf * 16 + cc) * 64;
      areg[mf][0] = *(const bf16x8*)(r + sw0);
      areg[mf][1] = *(const bf16x8*)(r + sw1);
    }
#pragma unroll
    for (int nf = 0; nf < 2; ++nf) {
      const unsigned short* r = Bb + (wn * 64 + nf * 16 + cc) * 64;
      breg[nf][0] = *(const bf16x8*)(r + sw0);
      breg[nf][1] = *(const bf16x8*)(r + sw1);
    }
    __builtin_amdgcn_s_barrier();
    asm volatile("s_waitcnt lgkmcnt(0)" ::: "memory");
    __builtin_amdgcn_s_setprio(1);
#pragma unroll
    for (int mf = 0; mf < 4; ++mf)
#pragma unroll
      for (int nf = 0; nf < 2; ++nf) {
        acc[mf][nf] = MF(areg[mf][0], breg[nf][0], acc[mf][nf]);
        acc[mf][nf] = MF(areg[mf][1], breg[nf][1], acc[mf][nf]);
      }
    __builtin_amdgcn_s_setprio(0);
    __builtin_amdgcn_s_barrier();

    // ---- phase 2: read B(nf2-3); MFMA (mf0-3 x nf2-3)
#pragma unroll
    for (int nf = 2; nf < 4; ++nf) {
      const unsigned short* r = Bb + (wn * 64 + nf * 16 + cc) * 64;
      breg[nf][0] = *(const bf16x8*)(r + sw0);
      breg[nf][1] = *(const bf16x8*)(r + sw1);
    }
    __builtin_amdgcn_s_barrier();
    asm volatile("s_waitcnt lgkmcnt(0)" ::: "memory");
    __builtin_amdgcn_s_setprio(1);
#pragma unroll
    for (int mf = 0; mf < 4; ++mf)
#pragma unroll
      for (int nf = 2; nf < 4; ++nf) {
        acc[mf][nf] = MF(areg[mf][0], breg[nf][0], acc[mf][nf]);
        acc[mf][nf] = MF(areg[mf][1], breg[nf][1], acc[mf][nf]);
      }
    __builtin_amdgcn_s_setprio(0);
    __builtin_amdgcn_s_barrier();   // all B-LDS reads of tile kt complete past here

    // ---- phase 3: read A(mf4-7); stage B(t+2) into buf p; MFMA (mf4-7 x nf2-3)
#pragma unroll
    for (int mf = 0; mf < 4; ++mf) {
      const unsigned short* r = Ab + (wm * 128 + (mf + 4) * 16 + cc) * 64;
      areg[mf][0] = *(const bf16x8*)(r + sw0);
      areg[mf][1] = *(const bf16x8*)(r + sw1);
    }
    stageB(p, ts);
    __builtin_amdgcn_s_barrier();
    asm volatile("s_waitcnt lgkmcnt(0)" ::: "memory");
    __builtin_amdgcn_s_setprio(1);
#pragma unroll
    for (int mf = 0; mf < 4; ++mf)
#pragma unroll
      for (int nf = 2; nf < 4; ++nf) {
        acc[mf + 4][nf] = MF(areg[mf][0], breg[nf][0], acc[mf + 4][nf]);
        acc[mf + 4][nf] = MF(areg[mf][1], breg[nf][1], acc[mf + 4][nf]);
      }
    __builtin_amdgcn_s_setprio(0);
    __builtin_amdgcn_s_barrier();   // all A-LDS reads of tile kt complete past here

    // ---- phase 4: stage A(t+2); vmcnt(8) (tile kt+1 landed); MFMA (mf4-7 x nf0-1)
    stageA(p, ts);
    asm volatile("s_waitcnt vmcnt(8)" ::: "memory");
    __builtin_amdgcn_s_setprio(1);
#pragma unroll
    for (int mf = 0; mf < 4; ++mf)
#pragma unroll
      for (int nf = 0; nf < 2; ++nf) {
        acc[mf + 4][nf] = MF(areg[mf][0], breg[nf][0], acc[mf + 4][nf]);
        acc[mf + 4][nf] = MF(areg[mf][1], breg[nf][1], acc[mf + 4][nf]);
      }
    __builtin_amdgcn_s_setprio(0);
    __builtin_amdgcn_s_barrier();
  }

  asm volatile("s_waitcnt vmcnt(0)" ::: "memory");   // drain clamped tail stages

  if (G == 1) {
    // ---- epilogue: wave-local SiLU: v1 = acc[mf][cf], v3 = acc[mf][cf+2] ----
#pragma unroll
    for (int mf = 0; mf < 8; ++mf) {
      int rlb = wm * 128 + mf * 16 + hi * 4;
#pragma unroll
      for (int cf = 0; cf < 2; ++cf) {
        int col = nb * 128 + wn * 32 + cf * 16 + cc;
#pragma unroll
        for (int r = 0; r < 4; ++r) {
          int row = rlb + r;
          if (m0 + row < cnt) {
            float v1 = acc[mf][cf][r], v3 = acc[mf][cf + 2][r];
            float h = v1 / (1.0f + __expf(-v1)) * v3;
            hid_out[(size_t)(off + m0 + row) * KHID + col] = f2bf(h);
          }
        }
      }
    }
  } else {
    // ---- epilogue: scale by routing weight, atomic accumulate into out ----
#pragma unroll
    for (int mf = 0; mf < 8; ++mf) {
      int rlb = wm * 128 + mf * 16 + hi * 4;
#pragma unroll
      for (int r = 0; r < 4; ++r) {
        int row = rlb + r;
        if (m0 + row < cnt) {
          int prow = off + m0 + row;
          int tok = ptok[prow];
          float w = prw[prow];
          float* op = out + (size_t)tok * KDIM + nb * 256 + wn * 64;
#pragma unroll
          for (int nf = 0; nf < 4; ++nf)
            unsafeAtomicAdd(&op[nf * 16 + cc], acc[mf][nf][r] * w);
        }
      }
    }
  }
}

__global__ __launch_bounds__(512, 2) void gemm1_kernel(
    const unsigned short* __restrict__ A, const unsigned short* __restrict__ B0,
    const unsigned short* __restrict__ B1, const int* __restrict__ meta,
    const int* __restrict__ ptok, unsigned short* __restrict__ hid_out) {
  gemm_body<1>(A, B0, B1, meta, ptok, nullptr, hid_out, nullptr);
}

__global__ __launch_bounds__(512, 2) void gemm2_kernel(
    const unsigned short* __restrict__ A, const unsigned short* __restrict__ B0,
    const int* __restrict__ meta, const int* __restrict__ ptok,
    const float* __restrict__ prw, float* __restrict__ out) {
  gemm_body<2>(A, B0, nullptr, meta, ptok, prw, nullptr, out);
}

extern "C" void kernel_launch(void* const* d_in, const int* in_sizes, int n_in,
                              void* d_out, int out_size, void* d_ws, size_t ws_size,
                              hipStream_t stream) {
  const float* x    = (const float*)d_in[0];
  const float* rwgt = (const float*)d_in[1];
  const float* w1   = (const float*)d_in[2];
  const float* w3   = (const float*)d_in[3];
  const float* w2   = (const float*)d_in[4];
  float* out = (float*)d_out;

  char* ws = (char*)d_ws;
  const size_t OFF_META = 0;
  const size_t OFF_SEL  = 512;
  const size_t OFF_RWT  = OFF_SEL  + (size_t)NPAIR * 4;
  const size_t OFF_PTOK = OFF_RWT  + (size_t)NPAIR * 4;
  const size_t OFF_PRW  = OFF_PTOK + (size_t)NPAIR * 4;
  const size_t OFF_LSL  = OFF_PRW  + (size_t)NPAIR * 4;
  const size_t OFF_BLK  = OFF_LSL  + (size_t)NPAIR * 4;
  const size_t OFF_XB   = OFF_BLK  + (size_t)RBLK * NEXP * 4;           // 512-aligned
  const size_t OFF_W1B  = OFF_XB   + (size_t)TTOK * KDIM * 2;
  const size_t OFF_W3B  = OFF_W1B  + (size_t)NEXP * KHID * KDIM * 2;
  const size_t OFF_W2B  = OFF_W3B  + (size_t)NEXP * KHID * KDIM * 2;
  const size_t OFF_HID  = OFF_W2B  + (size_t)NEXP * KDIM * KHID * 2;
  const size_t END      = OFF_HID  + (size_t)(NPAIR + 256) * KHID * 2;  // ~177 MiB
  if (ws_size < END) return;  // ws too small: fail safely (visible as absmax fail)

  int*   meta = (int*)(ws + OFF_META);
  int*   sel  = (int*)(ws + OFF_SEL);
  float* rwt  = (float*)(ws + OFF_RWT);
  int*   ptok = (int*)(ws + OFF_PTOK);
  float* prw  = (float*)(ws + OFF_PRW);
  int*   lsl  = (int*)(ws + OFF_LSL);
  int*   blkc = (int*)(ws + OFF_BLK);
  unsigned short* xb  = (unsigned short*)(ws + OFF_XB);
  unsigned short* w1b = (unsigned short*)(ws + OFF_W1B);
  unsigned short* w3b = (unsigned short*)(ws + OFF_W3B);
  unsigned short* w2b = (unsigned short*)(ws + OFF_W2B);
  unsigned short* hid = (unsigned short*)(ws + OFF_HID);

  hipMemsetAsync(d_out, 0, (size_t)out_size * 4, stream);

  convert_kernel<<<28672, 256, 0, stream>>>(
      (const float4*)x, (const float4*)w1, (const float4*)w3, (const float4*)w2,
      (uint4*)xb, (uint4*)w1b, (uint4*)w3b, (uint4*)w2b);
  router_kernel<<<RBLK, 256, 0, stream>>>(x, rwgt, out, sel, rwt, lsl, blkc);
  scan_kernel<<<1, 64, 0, stream>>>(blkc, meta);
  fill_kernel<<<NPAIR / 256, 256, 0, stream>>>(sel, rwt, lsl, blkc, meta, ptok, prw);
  gemm1_kernel<<<dim3(16, 32, NEXP), 512, 0, stream>>>(xb, w1b, w3b, meta, ptok, hid);
  gemm2_kernel<<<dim3(4, 32, NEXP), 512, 0, stream>>>(hid, w2b, meta, ptok, prw, out);
}